// Round 1
// baseline (117.602 us; speedup 1.0000x reference)
//
#include <hip/hip_runtime.h>
#include <math.h>

// Problem constants (reference: B=16, S=8192, D=256; k = S/4 = 2048)
#define SEQ   8192
#define DIM   256
#define NBAT  16
#define NODD  4096   // number of odd lags in the Dirichlet kernel

// out[b,s,d] = y[b,s]*W[d] + bias[d], where
// y = Re(IFFT(lowpass(FFT(x)))), x = char_ids/255.
// lowpass keeps f in [-2048, 2047]  =>  circular conv with
// K[0]=0.5, K[even]=0, K[odd delta] = (-1)^((delta-1)/2) * cot(pi*delta/8192)/8192.

__global__ __launch_bounds__(256)
void ktab_kernel(float* __restrict__ kt) {
    int j = blockIdx.x * 256 + threadIdx.x;   // j in [0, 4096): delta = 2j+1
    if (j >= NODD) return;
    int delta = 2 * j + 1;
    double ang = M_PI * (double)delta / (double)SEQ;
    double v = (cos(ang) / sin(ang)) / (double)SEQ;
    if (j & 1) v = -v;                         // (-1)^((delta-1)/2) = (-1)^j
    kt[j] = (float)v;
}

__global__ __launch_bounds__(256)
void spectral_kernel(const int* __restrict__ ids,
                     const float* __restrict__ W,
                     const float* __restrict__ bias,
                     const float* __restrict__ kt,
                     float* __restrict__ out) {
    __shared__ float xs[SEQ];    // full x row: 32 KB
    __shared__ float ks[NODD];   // odd-lag kernel: 16 KB
    __shared__ float ys[256];    // this block's filtered outputs

    const int bidx = blockIdx.x >> 5;          // 32 chunks of 256 outputs per row
    const int s0   = (blockIdx.x & 31) * 256;
    const int t    = threadIdx.x;

    // Stage x row (normalized) and K into LDS.
    const int* row = ids + bidx * SEQ;
    for (int i = t; i < SEQ; i += 256) xs[i] = (float)row[i] * (1.0f / 255.0f);
    for (int i = t; i < NODD; i += 256) ks[i] = kt[i];
    __syncthreads();

    // 4096-tap circular convolution (odd lags only).
    const int s = s0 + t;
    float acc = 0.5f * xs[s];
    #pragma unroll 8
    for (int j = 0; j < NODD; ++j) {
        int idx = (s - 1 - 2 * j) & (SEQ - 1);   // (s - delta) mod SEQ, two's-complement AND ok
        acc += xs[idx] * ks[j];
    }
    ys[t] = acc;
    __syncthreads();

    // Broadcast write: out[bidx][s0+i][d] = ys[i]*W[d] + bias[d].
    // Wave w handles s-rows i = w, w+4, ...; lanes cover all 256 d as float4.
    const int d = (t & 63) * 4;
    const float4 w4 = *(const float4*)(W + d);
    const float4 b4 = *(const float4*)(bias + d);
    float* orow = out + ((long long)bidx * SEQ + s0) * DIM;
    for (int i = (t >> 6); i < 256; i += 4) {
        const float y = ys[i];
        float4 v;
        v.x = fmaf(y, w4.x, b4.x);
        v.y = fmaf(y, w4.y, b4.y);
        v.z = fmaf(y, w4.z, b4.z);
        v.w = fmaf(y, w4.w, b4.w);
        *(float4*)(orow + (long long)i * DIM + d) = v;
    }
}

extern "C" void kernel_launch(void* const* d_in, const int* in_sizes, int n_in,
                              void* d_out, int out_size, void* d_ws, size_t ws_size,
                              hipStream_t stream) {
    const int*   ids  = (const int*)d_in[0];    // char_ids (B*S,), int32
    const float* W    = (const float*)d_in[1];  // (D,1) flat = D floats
    const float* bias = (const float*)d_in[2];  // (D,)
    float* out = (float*)d_out;                 // (B,S,D) float32
    float* kt  = (float*)d_ws;                  // 4096 floats of scratch

    ktab_kernel<<<NODD / 256, 256, 0, stream>>>(kt);
    spectral_kernel<<<NBAT * 32, 256, 0, stream>>>(ids, W, bias, kt, out);
}

// Round 2
// 83.745 us; speedup vs baseline: 1.4043x; 1.4043x over previous
//
#include <hip/hip_runtime.h>
#include <math.h>

// Problem: B=16, S=8192, D=256; lowpass keep |f| < 2048.
// out[b,s,d] = y[b,s]*W[d] + bias[d], y = x conv K (circular), x = ids/255.
// K[0]=0.5 (handled separately), K[odd delta=2j+1] = (-1)^j*cot(pi*delta/8192)/8192,
// K[even!=0]=0.

#define SEQ    8192
#define HSEQ   4096
#define DIM    256
#define NBAT   16
#define TABF   8208          // floats per parity table (doubled circular + pad)
#define ROWF   (2*TABF)
#define KTABF  4096
#define OUTB   128           // outputs per block
#define NSLICE 32            // tap slices (T)
#define TAPS_PER (HSEQ/NSLICE)  // 128 taps per thread
// thread layout: p = t>>7 (parity), u = t&127, h = u>>2 (slice), m = u&3 (group of 16 outputs)

__global__ __launch_bounds__(256)
void prep_kernel(const int* __restrict__ ids, float* __restrict__ ws) {
    const int idx = blockIdx.x * 256 + threadIdx.x;
    const int nthr = gridDim.x * 256;

    // K table (double precision build)
    for (int j = idx; j < KTABF; j += nthr) {
        int delta = 2 * j + 1;
        double ang = M_PI * (double)delta / (double)SEQ;
        double v = (cos(ang) / sin(ang)) / (double)SEQ;
        if (j & 1) v = -v;
        ws[j] = (float)v;
    }

    // Packed per-row parity tables:
    //  Te[ii] = x_even[(ii-3) & 4095]   (read by p=1 threads, offset 3 for alignment)
    //  To[ii] = x_odd [ ii    & 4095]   (read by p=0 threads)
    float* tab = ws + KTABF;
    const float inv255 = 1.0f / 255.0f;
    const int total = NBAT * ROWF;
    for (int i = idx; i < total; i += nthr) {
        int b   = i / ROWF;
        int rem = i - b * ROWF;
        int pc  = rem / TABF;            // 0 = Te, 1 = To
        int ii  = rem - pc * TABF;
        const int* row = ids + b * SEQ;
        float v;
        if (pc == 0) { int src = (ii - 3) & (HSEQ - 1); v = (float)row[2 * src]     * inv255; }
        else         { int src =  ii      & (HSEQ - 1); v = (float)row[2 * src + 1] * inv255; }
        tab[i] = v;
    }
}

__global__ __launch_bounds__(256)
void conv_kernel(const int* __restrict__ ids,
                 const float* __restrict__ ws,
                 const float* __restrict__ W,
                 const float* __restrict__ bias,
                 float* __restrict__ out) {
    __shared__ float red[NSLICE][OUTB];  // 16 KB, XOR-swizzled columns
    __shared__ float ys[OUTB];

    const float* kd  = ws;
    const float* tab = ws + KTABF;

    const int t = threadIdx.x;
    const int p = t >> 7;        // parity of output position
    const int u = t & 127;
    const int h = u >> 2;        // tap slice 0..31
    const int m = u & 3;         // output group (16 outputs each)
    const int row = blockIdx.x >> 6;
    const int s0  = (blockIdx.x & 63) * OUTB;

    // i0 = packed-array base index for this thread's output group.
    const int i0 = (s0 >> 1) + 16 * m - 1 + p;
    // p=1 reads Te (first table), p=0 reads To (second table).
    const float* tp = tab + row * ROWF + (p ? 0 : TABF);
    const int Bc = i0 + HSEQ - 31 + (p ? 3 : 0);   // window base const; Bc-J is mult of 4

    float acc[16];
    #pragma unroll
    for (int r = 0; r < 16; ++r) acc[r] = 0.f;

    for (int c = 0; c < TAPS_PER / 32; ++c) {
        const int J = h * TAPS_PER + c * 32;

        // Load 48-float x window and 32-float K chunk into registers.
        const float4* xb = (const float4*)(tp + (Bc - J));
        float xw[48];
        #pragma unroll
        for (int q = 0; q < 12; ++q) {
            const float4 v = xb[q];
            xw[4*q+0] = v.x; xw[4*q+1] = v.y; xw[4*q+2] = v.z; xw[4*q+3] = v.w;
        }
        const float4* kb = (const float4*)(kd + J);
        float kw[32];
        #pragma unroll
        for (int q = 0; q < 8; ++q) {
            const float4 v = kb[q];
            kw[4*q+0] = v.x; kw[4*q+1] = v.y; kw[4*q+2] = v.z; kw[4*q+3] = v.w;
        }

        // acc[r] += K[J+jj] * x_window[31 - jj + r]   (all register operands)
        #pragma unroll
        for (int jj = 0; jj < 32; ++jj) {
            const float kj = kw[jj];
            #pragma unroll
            for (int r = 0; r < 16; ++r) {
                acc[r] = fmaf(kj, xw[31 - jj + r], acc[r]);
            }
        }
    }

    // Scatter partials: output o = p + 32m + 2r; slot/column XOR-swizzled so both
    // the write (per-r) and the read (per-k) hit distinct banks.
    const int slot = (h + 8 * m) & 31;
    #pragma unroll
    for (int r = 0; r < 16; ++r) {
        const int o = p + 32 * m + 2 * r;
        red[slot][o ^ slot] = acc[r];
    }
    __syncthreads();

    if (t < OUTB) {
        const int o = t;
        float s = 0.f;
        #pragma unroll
        for (int k = 0; k < NSLICE; ++k) s += red[k][o ^ k];
        s += 0.5f * (float)ids[row * SEQ + s0 + o] * (1.0f / 255.0f);
        ys[o] = s;
    }
    __syncthreads();

    // Broadcast write: out[row][s0+i][d] = ys[i]*W[d] + bias[d]
    const int d = (t & 63) * 4;
    const float4 w4 = *(const float4*)(W + d);
    const float4 b4 = *(const float4*)(bias + d);
    float* orow = out + ((long long)row * SEQ + s0) * DIM;
    for (int i = (t >> 6); i < OUTB; i += 4) {
        const float y = ys[i];
        float4 v;
        v.x = fmaf(y, w4.x, b4.x);
        v.y = fmaf(y, w4.y, b4.y);
        v.z = fmaf(y, w4.z, b4.z);
        v.w = fmaf(y, w4.w, b4.w);
        *(float4*)(orow + (long long)i * DIM + d) = v;
    }
}

extern "C" void kernel_launch(void* const* d_in, const int* in_sizes, int n_in,
                              void* d_out, int out_size, void* d_ws, size_t ws_size,
                              hipStream_t stream) {
    const int*   ids  = (const int*)d_in[0];
    const float* W    = (const float*)d_in[1];
    const float* bias = (const float*)d_in[2];
    float* out = (float*)d_out;
    float* ws  = (float*)d_ws;   // [K 4096][16 rows x 2 x 8208] = ~1.05 MB

    prep_kernel<<<512, 256, 0, stream>>>(ids, ws);
    conv_kernel<<<NBAT * (SEQ / OUTB), 256, 0, stream>>>(ids, ws, W, bias, out);
}

// Round 3
// 76.713 us; speedup vs baseline: 1.5330x; 1.0917x over previous
//
#include <hip/hip_runtime.h>
#include <math.h>

// B=16, S=8192, D=256. out[b,s,d] = y[b,s]*W[d] + bias[d],
// y = lowpass(x) (keep |f|<2048), x = ids/255.
// Parity decomposition: y[2i]   = 0.5*x_e[i] + sum_j Kp[j]*x_o[(i-1-j) mod 4096]
//                       y[2i+1] = 0.5*x_o[i] + sum_j Kp[j]*x_e[(i-j)   mod 4096]
// Kp[j] = K[2j+1] = (-1)^j * cot(pi*(2j+1)/8192) / 8192.

#define SEQ    8192
#define HSEQ   4096
#define DIM    256
#define NBAT   16
#define OUTB   256
#define TBL_L  4384           // logical floats per parity table (covers wrap + slack)
#define TO_OFF 5488           // phys offset of To; quad-diff vs Te = 4 (mod 8)
#define LDSF   (TO_OFF + 5480)

__device__ __forceinline__ int physf(int g) { return g + ((g >> 4) << 2); }

__global__ __launch_bounds__(256)
void ktab_kernel(float* __restrict__ kt) {
    int j = blockIdx.x * 256 + threadIdx.x;   // delta = 2j+1
    if (j >= HSEQ) return;
    int delta = 2 * j + 1;
    double ang = M_PI * (double)delta / (double)SEQ;
    double v = (cos(ang) / sin(ang)) / (double)SEQ;
    if (j & 1) v = -v;
    kt[j] = (float)v;
}

__global__ __launch_bounds__(256)
void spectral_kernel(const int* __restrict__ ids,
                     const float* __restrict__ kd,
                     const float* __restrict__ W,
                     const float* __restrict__ bias,
                     float* __restrict__ out) {
    __shared__ float ts[LDSF];        // Te @0, To @TO_OFF (pad-swizzled)
    __shared__ float red[16][264];    // slice partials (+8 row pad)
    __shared__ float ys[OUTB];

    const int t    = threadIdx.x;
    const int rowi = blockIdx.x >> 5;           // 32 blocks per row
    const int s0   = (blockIdx.x & 31) * OUTB;
    const int ib   = s0 >> 1;                   // parity-packed output base

    // ---- stage parity tables into LDS (pad-swizzled) ----
    const int* row = ids + rowi * SEQ;
    const float inv255 = 1.0f / 255.0f;
    const int loTe = ib - 4127;                 // Te[g] = x_e[(g+loTe) & 4095]
    const int loTo = ib - 4128;                 // To[g] = x_o[(g+loTo) & 4095]
    for (int g = t; g < TBL_L; g += 256) {
        int se = (g + loTe) & (HSEQ - 1);
        int so = (g + loTo) & (HSEQ - 1);
        int ph = physf(g);
        ts[ph]          = (float)row[2 * se]     * inv255;
        ts[TO_OFF + ph] = (float)row[2 * so + 1] * inv255;
    }
    __syncthreads();

    // lane roles: w = wave, h = tap subslice, p = output parity, m = output group
    const int w = t >> 6, l = t & 63;
    const int h = l >> 4, p = (l >> 3) & 1, m = l & 7;
    // p=0 (even outputs) reads x_o (To); p=1 (odd outputs) reads x_e (Te)
    const float* tp = ts + (p ? 0 : TO_OFF);

    float acc[16];
    #pragma unroll
    for (int r = 0; r < 16; ++r) acc[r] = 0.f;

    const int Jbase = 1024 * w + 256 * h;       // this lane's 256-tap slice
    #pragma unroll 4
    for (int c = 0; c < 8; ++c) {
        const int J  = Jbase + 32 * c;
        const int gs = 16 * m + 4096 - J;       // window start, ≡0 mod 16
        const float4* xb = (const float4*)(tp + physf(gs));
        float xw[48];                            // xw[u] = table[gs+u]
        #pragma unroll
        for (int q = 0; q < 12; ++q) {
            const float4 v = xb[q + (q >> 2)];   // quads {0,1,2,3,5,6,7,8,10,11,12,13}
            xw[4*q+0] = v.x; xw[4*q+1] = v.y; xw[4*q+2] = v.z; xw[4*q+3] = v.w;
        }
        const float4* kb = (const float4*)(kd + J);   // uniform per 16 lanes, L1-hit
        float kw[32];
        #pragma unroll
        for (int q = 0; q < 8; ++q) {
            const float4 v = kb[q];
            kw[4*q+0] = v.x; kw[4*q+1] = v.y; kw[4*q+2] = v.z; kw[4*q+3] = v.w;
        }
        // acc[r] += Kp[J+jj] * table[gs + 31 - jj + r]
        #pragma unroll
        for (int jj = 0; jj < 32; ++jj) {
            const float kj = kw[jj];
            #pragma unroll
            for (int r = 0; r < 16; ++r)
                acc[r] = fmaf(kj, xw[31 - jj + r], acc[r]);
        }
    }

    // ---- cross-slice reduction ----
    const int sl = 4 * w + h;
    const int ob = 128 * p + 16 * m;
    #pragma unroll
    for (int r = 0; r < 16; ++r) red[sl][ob + r] = acc[r];
    __syncthreads();

    {
        const int o = t, p2 = t >> 7, io = t & 127;
        float s = 0.f;
        #pragma unroll
        for (int k = 0; k < 16; ++k) s += red[k][o];
        const int gc = io + (p2 ? 4128 : 4127);           // center tap x_same_parity[i]
        const float xc = p2 ? ts[TO_OFF + physf(gc)] : ts[physf(gc)];
        ys[2 * io + p2] = s + 0.5f * xc;
    }
    __syncthreads();

    // ---- broadcast write: out[rowi][s0+i][d] = ys[i]*W[d] + bias[d] ----
    const int d = (t & 63) * 4;
    const float4 w4 = *(const float4*)(W + d);
    const float4 b4 = *(const float4*)(bias + d);
    float* orow = out + ((long long)rowi * SEQ + s0) * DIM;
    for (int i = t >> 6; i < OUTB; i += 4) {
        const float y = ys[i];
        float4 v;
        v.x = fmaf(y, w4.x, b4.x);
        v.y = fmaf(y, w4.y, b4.y);
        v.z = fmaf(y, w4.z, b4.z);
        v.w = fmaf(y, w4.w, b4.w);
        *(float4*)(orow + (long long)i * DIM + d) = v;
    }
}

extern "C" void kernel_launch(void* const* d_in, const int* in_sizes, int n_in,
                              void* d_out, int out_size, void* d_ws, size_t ws_size,
                              hipStream_t stream) {
    const int*   ids  = (const int*)d_in[0];
    const float* W    = (const float*)d_in[1];
    const float* bias = (const float*)d_in[2];
    float* out = (float*)d_out;
    float* kt  = (float*)d_ws;                  // 4096 floats

    ktab_kernel<<<HSEQ / 256, 256, 0, stream>>>(kt);
    spectral_kernel<<<NBAT * (SEQ / OUTB), 256, 0, stream>>>(ids, kt, W, bias, out);
}

// Round 4
// 72.170 us; speedup vs baseline: 1.6295x; 1.0629x over previous
//
#include <hip/hip_runtime.h>
#include <math.h>

// B=16, S=8192, D=256. out[b,s,d] = y[b,s]*W[d] + bias[d],
// y = lowpass(x) keep |f|<2048, x = ids/255.
// Parity split: y[2i]   = 0.5*x_e[i] + sum_j Kp[j]*x_o[(i-1-j) mod 4096]
//               y[2i+1] = 0.5*x_o[i] + sum_j Kp[j]*x_e[(i-j)   mod 4096]
// Kp[j] = (-1)^j * cot(pi*(2j+1)/8192) / 8192.
// Stage 1 (conv): grid (row, outseg, tapseg) -> partial sums in ws.
// Stage 2 (write): sum 4 partials + center tap, broadcast over D.

#define SEQ    8192
#define HSEQ   4096
#define DIM    256
#define NBAT   16

#define TBLF   1280        // logical floats per parity window
#define TO_B   1616        // phys float offset of To (byte 6464 == 64 mod 128)
#define TABTOT 3216
#define REDW   132         // reduction row stride (128 + 4 pad)

__device__ __forceinline__ int physf(int g) { return g + ((g >> 4) << 2); }

__global__ __launch_bounds__(256)
void ktab_kernel(float* __restrict__ kt) {
    int j = blockIdx.x * 256 + threadIdx.x;    // delta = 2j+1
    if (j >= HSEQ) return;
    int delta = 2 * j + 1;
    double ang = M_PI * (double)delta / (double)SEQ;
    double v = (cos(ang) / sin(ang)) / (double)SEQ;
    if (j & 1) v = -v;
    kt[j] = (float)v;
}

__global__ __launch_bounds__(256)
void conv_kernel(const int* __restrict__ ids,
                 const float* __restrict__ kd,
                 float* __restrict__ ypart) {
    __shared__ float ts[TABTOT];       // Te @0, To @TO_B (pad-swizzled)
    __shared__ float red[32 * REDW];   // [pm 32][slice 8 * 16] partials

    const int t   = threadIdx.x;
    const int blk = blockIdx.x;
    const int g   = blk & 3;           // tap segment (1024 taps)
    const int o   = (blk >> 2) & 15;   // output segment (256 packed per parity)
    const int r   = blk >> 6;          // batch row
    const int i0  = o << 8;

    // ---- stage windows ----
    const int* row = ids + r * SEQ;
    const float inv255 = 1.0f / 255.0f;
    const int lo_o = i0 - (g << 10) - 1024;   // To[u] = x_o[(u+lo_o)&4095]
    const int lo_e = lo_o + 1;                // Te[u] = x_e[(u+lo_e)&4095]
    for (int u = t; u < TBLF; u += 256) {
        int se = (u + lo_e) & (HSEQ - 1);
        int so = (u + lo_o) & (HSEQ - 1);
        int ph = physf(u);
        ts[ph]        = (float)row[2 * se]     * inv255;   // Te
        ts[TO_B + ph] = (float)row[2 * so + 1] * inv255;   // To
    }
    __syncthreads();

    // lane roles: w = wave (256-tap slice), h = 128-tap half, p = parity, m = out group
    const int w = t >> 6, l = t & 63;
    const int h = l >> 5, p = (l >> 4) & 1, m = l & 15;
    const float* tp = ts + (p ? 0 : TO_B);   // even outputs read x_odd, odd read x_even
    const int Jl0 = (w << 8) + (h << 7);

    float acc[16];
    #pragma unroll
    for (int q = 0; q < 16; ++q) acc[q] = 0.f;

    #pragma unroll 1
    for (int c = 0; c < 4; ++c) {
        const int Jloc = Jl0 + (c << 5);
        const int us   = (m << 4) + 992 - Jloc;        // window start, mult of 16
        const float4* xb = (const float4*)(tp + physf(us));
        float xw[48];
        #pragma unroll
        for (int q = 0; q < 12; ++q) {
            const float4 v = xb[q + (q >> 2)];          // phys quads skip every 5th
            xw[4*q+0] = v.x; xw[4*q+1] = v.y; xw[4*q+2] = v.z; xw[4*q+3] = v.w;
        }
        const float4* kb = (const float4*)(kd + (g << 10) + Jloc);
        float kw[32];
        #pragma unroll
        for (int q = 0; q < 8; ++q) {
            const float4 v = kb[q];
            kw[4*q+0] = v.x; kw[4*q+1] = v.y; kw[4*q+2] = v.z; kw[4*q+3] = v.w;
        }
        // acc[q] += Kp[J+jj] * table[us + 31 - jj + q]
        #pragma unroll
        for (int jj = 0; jj < 32; ++jj) {
            const float kj = kw[jj];
            #pragma unroll
            for (int q = 0; q < 16; ++q)
                acc[q] = fmaf(kj, xw[31 - jj + q], acc[q]);
        }
    }

    // ---- partial scatter + cross-slice reduction ----
    const int sl = (w << 1) | h;
    float4* rb = (float4*)(red + ((p << 4) | m) * REDW + (sl << 4));
    rb[0] = make_float4(acc[0],  acc[1],  acc[2],  acc[3]);
    rb[1] = make_float4(acc[4],  acc[5],  acc[6],  acc[7]);
    rb[2] = make_float4(acc[8],  acc[9],  acc[10], acc[11]);
    rb[3] = make_float4(acc[12], acc[13], acc[14], acc[15]);
    __syncthreads();

    const int m2 = t >> 4, r2 = t & 15;
    float se_ = 0.f, so_ = 0.f;
    #pragma unroll
    for (int s = 0; s < 8; ++s) {
        se_ += red[m2 * REDW + (s << 4) + r2];          // p=0 (even s)
        so_ += red[(16 + m2) * REDW + (s << 4) + r2];   // p=1 (odd s)
    }
    float2 v2; v2.x = se_; v2.y = so_;
    *(float2*)(ypart + (g * NBAT + r) * SEQ + ((i0 + (m2 << 4) + r2) << 1)) = v2;
}

__global__ __launch_bounds__(256)
void write_kernel(const int* __restrict__ ids,
                  const float* __restrict__ ypart,
                  const float* __restrict__ W,
                  const float* __restrict__ bias,
                  float* __restrict__ out) {
    __shared__ float ys[256];
    const int t  = threadIdx.x;
    const int r  = blockIdx.x >> 5;
    const int s0 = (blockIdx.x & 31) << 8;
    const int s  = s0 + t;

    float v = 0.f;
    #pragma unroll
    for (int g = 0; g < 4; ++g) v += ypart[(g * NBAT + r) * SEQ + s];
    v += 0.5f * (float)ids[r * SEQ + s] * (1.0f / 255.0f);
    ys[t] = v;
    __syncthreads();

    const int d = (t & 63) * 4;
    const float4 w4 = *(const float4*)(W + d);
    const float4 b4 = *(const float4*)(bias + d);
    float* orow = out + ((long long)r * SEQ + s0) * DIM;
    for (int i = t >> 6; i < 256; i += 4) {
        const float y = ys[i];
        float4 o4;
        o4.x = fmaf(y, w4.x, b4.x);
        o4.y = fmaf(y, w4.y, b4.y);
        o4.z = fmaf(y, w4.z, b4.z);
        o4.w = fmaf(y, w4.w, b4.w);
        *(float4*)(orow + (long long)i * DIM + d) = o4;
    }
}

extern "C" void kernel_launch(void* const* d_in, const int* in_sizes, int n_in,
                              void* d_out, int out_size, void* d_ws, size_t ws_size,
                              hipStream_t stream) {
    const int*   ids  = (const int*)d_in[0];
    const float* W    = (const float*)d_in[1];
    const float* bias = (const float*)d_in[2];
    float* out   = (float*)d_out;
    float* kt    = (float*)d_ws;            // 4096 floats
    float* ypart = (float*)d_ws + HSEQ;     // 4*16*8192 floats = 2 MB

    ktab_kernel<<<HSEQ / 256, 256, 0, stream>>>(kt);
    conv_kernel<<<NBAT * 16 * 4, 256, 0, stream>>>(ids, kt, ypart);
    write_kernel<<<NBAT * (SEQ / 256), 256, 0, stream>>>(ids, ypart, W, bias, out);
}